// Round 7
// baseline (358.293 us; speedup 1.0000x reference)
//
#include <hip/hip_runtime.h>

#define HW 512
#define NPIX (HW*HW)
#define NSAMP 64
#define KSEL 2621
#define NF 3
#define NQ (NF*NSAMP)
#define CAP 16384
#define CPAD 32     // cnt padding (uints) -> 128B per counter, no false sharing

#define HALO 3      // max filter halo
#define LSTR 520    // LDS row stride in floats (16B-aligned, bank-friendly)

#define ROWS_F 8    // fwd strip rows (round-6 lesson: ROWS=16 -> 54.8KB LDS +
                    // 112 VGPR -> 2 blocks/CU, 4 waves/SIMD, 64% stall)
#define TR_F (ROWS_F + 2*HALO)   // 14
#define ROWS_B 16   // bwd strip rows (memory-bound, fine at 2 blocks/CU)
#define TR_B (ROWS_B + 2*HALO)   // 22

// ===========================================================================
// Row-streaming conv: for each staged row y, load a K-wide window once and
// scatter-accumulate into acc[y-i]. Live set = v[K] + acc[R] (round-5
// lesson: 22-wide col windows at a forced 64-VGPR budget spilled ~550B/thread
// -> 638MB phantom HBM writes).
// ===========================================================================
template<int K, int R>
__device__ __forceinline__ void conv_rows_f64(
    const float (*xt)[LSTR], const double* __restrict__ wsm,
    int tx, double* __restrict__ acc)
{
  constexpr int ROFF = HALO - K/2;
  constexpr int COFF = 4 - K/2;
  #pragma unroll
  for (int y = 0; y < R + K - 1; ++y) {
    double v[K];
    #pragma unroll
    for (int j = 0; j < K; ++j)
      v[j] = (double)xt[y + ROFF][tx + j + COFF];
    #pragma unroll
    for (int i = 0; i < K; ++i) {
      const int r = y - i;                 // compile-time after unroll
      if (r >= 0 && r < R) {
        #pragma unroll
        for (int j = 0; j < K; ++j)
          acc[r] = fma(v[j], wsm[i*K + j], acc[r]);
      }
    }
  }
}

template<int K, int R>
__device__ __forceinline__ void conv_rows_f32(
    const float (*xt)[LSTR], const float* __restrict__ wsm,
    int tx, float* __restrict__ acc)
{
  constexpr int ROFF = HALO - K/2;
  constexpr int COFF = 4 - K/2;
  #pragma unroll
  for (int y = 0; y < R + K - 1; ++y) {
    float v[K];
    #pragma unroll
    for (int j = 0; j < K; ++j)
      v[j] = xt[y + ROFF][tx + j + COFF];
    #pragma unroll
    for (int i = 0; i < K; ++i) {
      const int r = y - i;
      if (r >= 0 && r < R) {
        #pragma unroll
        for (int j = 0; j < K; ++j)
          acc[r] = fmaf(v[j], wsm[i*K + j], acc[r]);
      }
    }
  }
}

// ===========================================================================
// Forward: full-width 512x8 strip, stage x once (coalesced float4, pow2
// index math), compute sim3/sim5/sim7 in fp64 (exact selection vs reference),
// level-1 hist (bits[30:20], 2048 bins) per filter.
// ===========================================================================
__global__ __launch_bounds__(512, 2) void fwd_all(
    const float* __restrict__ x,
    const float* __restrict__ w3, const float* __restrict__ w5,
    const float* __restrict__ w7,
    float* __restrict__ sims, unsigned* __restrict__ hist1)
{
  __shared__ float xt[TR_F][LSTR];
  __shared__ double wsm[49];
  __shared__ unsigned lh[2048];

  const int tid = threadIdx.x;
  const int s  = blockIdx.y;
  const int by = blockIdx.x * ROWS_F;
  const float* __restrict__ xs = x + (size_t)s*NPIX;

  // zero x-halo pads: cols 0..3 and 516..519, all TR_F rows
  if (tid < TR_F*8) {
    const int r = tid >> 3, c = tid & 7;
    xt[r][(c < 4) ? c : 512 + c] = 0.0f;
  }
  // stage TR_F rows x 128 float4 (data at float offset 4 -> 16B aligned)
  for (int idx = tid; idx < TR_F*128; idx += 512) {
    const int r = idx >> 7, c4 = idx & 127;
    const int gy = by + r - HALO;
    float4 v = make_float4(0.f, 0.f, 0.f, 0.f);
    if (gy >= 0 && gy < HW)
      v = ((const float4*)(xs + (size_t)gy*HW))[c4];
    *(float4*)&xt[r][4 + 4*c4] = v;
  }

  const int tx = tid;  // output column 0..511
  const float* const wp[NF] = {w3, w5, w7};

  #pragma unroll
  for (int f = 0; f < NF; ++f) {
    __syncthreads();                    // staging done / prev merge done
    if (tid < 49) wsm[tid] = (tid < (3+2*f)*(3+2*f)) ? (double)wp[f][tid] : 0.0;
    for (int i = tid; i < 2048; i += 512) lh[i] = 0;
    __syncthreads();

    double acc[ROWS_F];
    #pragma unroll
    for (int r = 0; r < ROWS_F; ++r) acc[r] = 0.0;
    if (f == 0)      conv_rows_f64<3, ROWS_F>(xt, wsm, tx, acc);
    else if (f == 1) conv_rows_f64<5, ROWS_F>(xt, wsm, tx, acc);
    else             conv_rows_f64<7, ROWS_F>(xt, wsm, tx, acc);

    float* __restrict__ so =
        sims + ((size_t)f*NSAMP + s)*NPIX + (size_t)by*HW + tx;
    #pragma unroll
    for (int r = 0; r < ROWS_F; ++r) {
      const float sv = (float)acc[r];
      so[(size_t)r*HW] = sv;
      atomicAdd(&lh[(__float_as_uint(sv) & 0x7fffffffu) >> 20], 1u);
    }
    __syncthreads();
    unsigned* __restrict__ gh = hist1 + ((size_t)f*NSAMP + s)*2048;
    for (int i = tid; i < 2048; i += 512) {
      const unsigned c = lh[i];
      if (c) atomicAdd(&gh[i], c);
    }
  }
}

// Level-1 scan: one block per q.
__global__ __launch_bounds__(256) void scan1_all(
    const unsigned* __restrict__ hist1, unsigned* __restrict__ prefix1,
    unsigned* __restrict__ krem1)
{
  const int q = blockIdx.x;
  const int t = threadIdx.x;
  const unsigned* __restrict__ h = hist1 + (size_t)q*2048;
  __shared__ unsigned part[256];
  unsigned sum = 0;
  #pragma unroll
  for (int i = 0; i < 8; ++i) sum += h[t*8 + i];
  part[t] = sum;
  __syncthreads();
  if (t == 0) {
    const unsigned kr = KSEL;
    unsigned cum = 0; int sc = 0;
    for (int c = 255; c >= 0; --c) {
      if (cum + part[c] >= kr) { sc = c; break; }
      cum += part[c];
    }
    unsigned cum2 = cum; int sb = sc*8;
    for (int b = sc*8 + 7; b >= sc*8; --b) {
      if (cum2 + h[b] >= kr) { sb = b; break; }
      cum2 += h[b];
    }
    prefix1[q] = ((unsigned)sb) << 20;
    krem1[q]   = kr - cum2;
  }
}

// Compaction: block-local LDS aggregation + ONE padded global atomic per
// block (round-3 lesson: per-element same-line device atomics -> 1.8 ms).
__global__ __launch_bounds__(256) void refine2_all(
    const float* __restrict__ sims, const unsigned* __restrict__ prefix1,
    unsigned* __restrict__ cntp, unsigned* __restrict__ cand)
{
  __shared__ unsigned sb[4096];
  __shared__ unsigned scnt, sbase;
  const int tid = threadIdx.x;
  const int q = blockIdx.y;
  if (tid == 0) scnt = 0;
  __syncthreads();

  const unsigned pb = prefix1[q] >> 20;
  const float4* __restrict__ p =
      (const float4*)(sims + (size_t)q*NPIX) + (size_t)blockIdx.x*1024;
  #pragma unroll
  for (int k = 0; k < 4; ++k) {
    const float4 v = p[k*256 + tid];
    const float f4[4] = {v.x, v.y, v.z, v.w};
    #pragma unroll
    for (int e = 0; e < 4; ++e) {
      const unsigned bits = __float_as_uint(f4[e]) & 0x7fffffffu;
      if ((bits >> 20) == pb) sb[atomicAdd(&scnt, 1u)] = bits;
    }
  }
  __syncthreads();
  const unsigned nb = scnt;
  if (tid == 0) sbase = nb ? atomicAdd(&cntp[(size_t)q*CPAD], nb) : 0u;
  __syncthreads();
  const unsigned base = sbase;
  for (unsigned i = tid; i < nb; i += 256) {
    const unsigned pos = base + i;
    if (pos < CAP) cand[(size_t)q*CAP + pos] = sb[i];
  }
}

// Levels 2+3 from the compact candidate list (exact full-scan fallback if
// the level-1 bin overflowed CAP). One block per q.
__global__ __launch_bounds__(256) void sel23_all(
    const unsigned* __restrict__ prefix1, const unsigned* __restrict__ krem1,
    const unsigned* __restrict__ cntp, const unsigned* __restrict__ cand,
    const float* __restrict__ sims, unsigned* __restrict__ thb)
{
  const int q = blockIdx.x;
  const int t = threadIdx.x;
  __shared__ unsigned lh[2048];
  __shared__ unsigned part[256];
  __shared__ unsigned sh_pfx2, sh_kr2;

  for (int i = t; i < 2048; i += 256) lh[i] = 0;
  __syncthreads();

  const unsigned n    = cntp[(size_t)q*CPAD];
  const unsigned pfx1 = prefix1[q];
  const unsigned* __restrict__ cq = cand + (size_t)q*CAP;
  const float*    __restrict__ sq = sims + (size_t)q*NPIX;
  const bool ok = (n <= CAP);

  if (ok) {
    for (unsigned i = t; i < n; i += 256)
      atomicAdd(&lh[(cq[i] >> 9) & 0x7ffu], 1u);
  } else {
    for (int i = t; i < NPIX; i += 256) {
      const unsigned b = __float_as_uint(sq[i]) & 0x7fffffffu;
      if ((b >> 20) == (pfx1 >> 20)) atomicAdd(&lh[(b >> 9) & 0x7ffu], 1u);
    }
  }
  __syncthreads();

  unsigned sum = 0;
  #pragma unroll
  for (int i = 0; i < 8; ++i) sum += lh[t*8 + i];
  part[t] = sum;
  __syncthreads();
  if (t == 0) {
    const unsigned kr = krem1[q];
    unsigned cum = 0; int sc = 0;
    for (int c = 255; c >= 0; --c) {
      if (cum + part[c] >= kr) { sc = c; break; }
      cum += part[c];
    }
    unsigned cum2 = cum; int sb = sc*8;
    for (int b = sc*8 + 7; b >= sc*8; --b) {
      if (cum2 + lh[b] >= kr) { sb = b; break; }
      cum2 += lh[b];
    }
    sh_pfx2 = pfx1 | (((unsigned)sb) << 9);
    sh_kr2  = kr - cum2;
  }
  __syncthreads();
  const unsigned pfx2 = sh_pfx2;

  for (int i = t; i < 512; i += 256) lh[i] = 0;
  __syncthreads();
  if (ok) {
    for (unsigned i = t; i < n; i += 256) {
      const unsigned b = cq[i];
      if ((b >> 9) == (pfx2 >> 9)) atomicAdd(&lh[b & 0x1ffu], 1u);
    }
  } else {
    for (int i = t; i < NPIX; i += 256) {
      const unsigned b = __float_as_uint(sq[i]) & 0x7fffffffu;
      if ((b >> 9) == (pfx2 >> 9)) atomicAdd(&lh[b & 0x1ffu], 1u);
    }
  }
  __syncthreads();

  part[t] = lh[2*t] + lh[2*t + 1];
  __syncthreads();
  if (t == 0) {
    const unsigned kr = sh_kr2;
    unsigned cum = 0; int sc = 0;
    for (int c = 255; c >= 0; --c) {
      if (cum + part[c] >= kr) { sc = c; break; }
      cum += part[c];
    }
    unsigned cum2 = cum; int sb = 2*sc;
    for (int b = 2*sc + 1; b >= 2*sc; --b) {
      if (cum2 + lh[b] >= kr) { sb = b; break; }
      cum2 += lh[b];
    }
    thb[q] = pfx2 | (unsigned)sb;
  }
}

// ===========================================================================
// Backward: per 512x16 strip, for each filter stage thresholded sim_f
// (coalesced float4, threshold applied per component), row-streaming fp32
// conv, accumulate across filters in regs, single write of out.
// ===========================================================================
__global__ __launch_bounds__(512, 2) void bwd_all(
    const float* __restrict__ sims,
    const float* __restrict__ w3, const float* __restrict__ w5,
    const float* __restrict__ w7,
    const unsigned* __restrict__ thb, float* __restrict__ out)
{
  __shared__ float xt[TR_B][LSTR];
  __shared__ float wsm[49];

  const int tid = threadIdx.x;
  const int s  = blockIdx.y;
  const int by = blockIdx.x * ROWS_B;
  const int tx = tid;
  const float* const wp[NF] = {w3, w5, w7};

  // zero x-halo pads once (never overwritten by staging)
  if (tid < TR_B*8) {
    const int r = tid >> 3, c = tid & 7;
    xt[r][(c < 4) ? c : 512 + c] = 0.0f;
  }

  float acc[ROWS_B];
  #pragma unroll
  for (int r = 0; r < ROWS_B; ++r) acc[r] = 0.0f;

  #pragma unroll
  for (int f = 0; f < NF; ++f) {
    __syncthreads();                    // pads done / prev conv done
    if (tid < 49) wsm[tid] = (tid < (3+2*f)*(3+2*f)) ? wp[f][tid] : 0.0f;
    const unsigned th = thb[f*NSAMP + s];
    const float* __restrict__ ss = sims + ((size_t)f*NSAMP + s)*NPIX;

    for (int idx = tid; idx < TR_B*128; idx += 512) {
      const int r = idx >> 7, c4 = idx & 127;
      const int gy = by + r - HALO;
      float4 v = make_float4(0.f, 0.f, 0.f, 0.f);
      if (gy >= 0 && gy < HW) {
        v = ((const float4*)(ss + (size_t)gy*HW))[c4];
        if ((__float_as_uint(v.x) & 0x7fffffffu) < th) v.x = 0.0f;
        if ((__float_as_uint(v.y) & 0x7fffffffu) < th) v.y = 0.0f;
        if ((__float_as_uint(v.z) & 0x7fffffffu) < th) v.z = 0.0f;
        if ((__float_as_uint(v.w) & 0x7fffffffu) < th) v.w = 0.0f;
      }
      *(float4*)&xt[r][4 + 4*c4] = v;
    }
    __syncthreads();

    if (f == 0)      conv_rows_f32<3, ROWS_B>(xt, wsm, tx, acc);
    else if (f == 1) conv_rows_f32<5, ROWS_B>(xt, wsm, tx, acc);
    else             conv_rows_f32<7, ROWS_B>(xt, wsm, tx, acc);
  }

  float* __restrict__ oo = out + (size_t)s*NPIX + (size_t)by*HW + tx;
  #pragma unroll
  for (int r = 0; r < ROWS_B; ++r)
    oo[(size_t)r*HW] = acc[r];
}

// ===========================================================================
extern "C" void kernel_launch(void* const* d_in, const int* in_sizes, int n_in,
                              void* d_out, int out_size, void* d_ws, size_t ws_size,
                              hipStream_t stream)
{
  const float* x  = (const float*)d_in[0];
  const float* w3 = (const float*)d_in[1];
  const float* w5 = (const float*)d_in[2];
  const float* w7 = (const float*)d_in[3];
  float* out = (float*)d_out;
  char* ws = (char*)d_ws;

  const size_t SIMS_B = (size_t)NF*NSAMP*NPIX*sizeof(float);   // 192 MB
  const size_t H1_B   = (size_t)NQ*2048*sizeof(unsigned);      // 1.5 MB
  const size_t CNT_B  = (size_t)NQ*CPAD*sizeof(unsigned);      // 24 KB

  float*    sims    = (float*)ws;
  unsigned* hist1   = (unsigned*)(ws + SIMS_B);
  unsigned* cntp    = hist1 + (size_t)NQ*2048;
  unsigned* prefix1 = cntp + (size_t)NQ*CPAD;
  unsigned* krem1   = prefix1 + NQ;
  unsigned* thb     = krem1 + NQ;
  unsigned* cand    = thb + NQ + NQ;   // spare NQ gap

  // zero hist1 + cntp (contiguous)
  hipMemsetAsync(hist1, 0, H1_B + CNT_B, stream);

  dim3 b512(512, 1, 1);
  dim3 fg(HW/ROWS_F, NSAMP, 1);   // 64 x 64 = 4096 blocks
  dim3 bg(HW/ROWS_B, NSAMP, 1);   // 32 x 64 = 2048 blocks
  fwd_all<<<fg, b512, 0, stream>>>(x, w3, w5, w7, sims, hist1);
  scan1_all<<<NQ, 256, 0, stream>>>(hist1, prefix1, krem1);
  dim3 rg(NPIX/4096, NQ, 1);
  refine2_all<<<rg, dim3(256,1,1), 0, stream>>>(sims, prefix1, cntp, cand);
  sel23_all<<<NQ, 256, 0, stream>>>(prefix1, krem1, cntp, cand, sims, thb);
  bwd_all<<<bg, b512, 0, stream>>>(sims, w3, w5, w7, thb, out);
}